// Round 1
// baseline (558.419 us; speedup 1.0000x reference)
//
#include <hip/hip_runtime.h>

#define DEVI __device__ __forceinline__

typedef __bf16 bf16x8 __attribute__((ext_vector_type(8)));
typedef float f32x4 __attribute__((ext_vector_type(4)));

// ---------- exact bf16 RNE helpers ----------
DEVI unsigned short f2bf(float f) {
  unsigned u = __float_as_uint(f);
  u = (u + 0x7FFFu + ((u >> 16) & 1u)) >> 16;
  return (unsigned short)u;
}
DEVI float bf2f(unsigned short h) { return __uint_as_float(((unsigned)h) << 16); }
DEVI float bf16r(float f) { return bf2f(f2bf(f)); }

// ---------- fast MXINT8 scale from block amax (amax normal, >0) ----------
DEVI void mx_scales(float amax, float& scale, float& inv) {
  unsigned eb = __float_as_uint(amax) & 0x7f800000u;
  scale = __uint_as_float(eb - (6u << 23));          // 2^(e-6)
  inv   = __uint_as_float((260u << 23) - eb);        // 2^(6-e)
}

DEVI unsigned short quantv(float v, float scale, float inv) {
  float qv = rintf(v * inv);                          // RNE, matches jnp.round
  qv = fminf(fmaxf(qv, -128.f), 127.f);
  return f2bf(qv * scale);                            // exact in bf16
}

DEVI void quant8(const float* h, float amax, unsigned short* q) {
  if (amax > 0.f) {
    float scale, inv;
    mx_scales(amax, scale, inv);
#pragma unroll
    for (int k = 0; k < 8; ++k) q[k] = quantv(h[k], scale, inv);
  } else {
#pragma unroll
    for (int k = 0; k < 8; ++k) q[k] = 0;
  }
}

// ---------- 16-lane (DPP row) max reduction on the VALU pipe ----------
template <int N>
DEVI float qmax_step(float x) {
  int y = __builtin_amdgcn_update_dpp(0, __float_as_int(x), 0x120 | N, 0xF, 0xF, true);
  return fmaxf(x, __int_as_float(y));
}
DEVI float quad_row_max(float x) {
  x = qmax_step<1>(x);
  x = qmax_step<2>(x);
  x = qmax_step<4>(x);
  x = qmax_step<8>(x);
  return x;
}

// ---------- async global->LDS 16B ----------
DEVI void gl2lds16(const void* g, void* l) {
  __builtin_amdgcn_global_load_lds(
      (__attribute__((address_space(1))) void*)const_cast<void*>(g),
      (__attribute__((address_space(3))) void*)l, 16, 0, 0);
}

DEVI uint4 pack8(const unsigned short* q) {
  uint4 o;
  o.x = (unsigned)q[0] | ((unsigned)q[1] << 16);
  o.y = (unsigned)q[2] | ((unsigned)q[3] << 16);
  o.z = (unsigned)q[4] | ((unsigned)q[5] << 16);
  o.w = (unsigned)q[6] | ((unsigned)q[7] << 16);
  return o;
}

// ---------- merged prep: W1 quant | W2 quant | LN+quant in ONE dispatch ----------
__global__ __launch_bounds__(256) void prep_k(const float* __restrict__ W1,
                                              const float* __restrict__ W2,
                                              const float* __restrict__ X,
                                              const float* __restrict__ lw,
                                              const float* __restrict__ lb,
                                              unsigned short* __restrict__ qW1,
                                              unsigned short* __restrict__ qW2,
                                              unsigned short* __restrict__ a1) {
  __shared__ float red[4];
  const int bid = blockIdx.x;
  const int t = threadIdx.x;
  if (bid < 16384) {
    const float* src = (bid < 8192) ? W1 : W2;
    unsigned short* dst = (bid < 8192) ? qW1 : qW2;
    size_t idx = (size_t)(bid & 8191) * 256 + t;   // 8 elems/thread
    float4 v0 = ((const float4*)src)[idx * 2];
    float4 v1 = ((const float4*)src)[idx * 2 + 1];
    float h[8] = {v0.x, v0.y, v0.z, v0.w, v1.x, v1.y, v1.z, v1.w};
    float amax = 0.f;
#pragma unroll
    for (int k = 0; k < 8; ++k) amax = fmaxf(amax, fabsf(h[k]));
    amax = fmaxf(amax, __shfl_xor(amax, 1));   // 4 consecutive lanes = one 32-block
    amax = fmaxf(amax, __shfl_xor(amax, 2));
    unsigned short q[8];
    quant8(h, amax, q);
    ((uint4*)dst)[idx] = pack8(q);
  } else {
    const int H = 2048;
    const int row = bid - 16384;
    const int lane = t & 63, wave = t >> 6;
    const float* xr = X + (size_t)row * H;
    float4 v0 = ((const float4*)xr)[2 * t];
    float4 v1 = ((const float4*)xr)[2 * t + 1];
    float x[8] = {bf16r(v0.x), bf16r(v0.y), bf16r(v0.z), bf16r(v0.w),
                  bf16r(v1.x), bf16r(v1.y), bf16r(v1.z), bf16r(v1.w)};
    float s = 0.f;
#pragma unroll
    for (int k = 0; k < 8; ++k) s += x[k];
#pragma unroll
    for (int o = 32; o; o >>= 1) s += __shfl_xor(s, o);
    if (lane == 0) red[wave] = s;
    __syncthreads();
    float mu = (red[0] + red[1] + red[2] + red[3]) * (1.0f / H);
    __syncthreads();
    float v = 0.f;
#pragma unroll
    for (int k = 0; k < 8; ++k) { float d = x[k] - mu; v += d * d; }
#pragma unroll
    for (int o = 32; o; o >>= 1) v += __shfl_xor(v, o);
    if (lane == 0) red[wave] = v;
    __syncthreads();
    float var = (red[0] + red[1] + red[2] + red[3]) * (1.0f / H);
    float rstd = 1.0f / sqrtf(var + 1e-5f);
    float h[8];
    float amax = 0.f;
#pragma unroll
    for (int k = 0; k < 8; ++k) {
      int col = t * 8 + k;
      h[k] = bf16r((x[k] - mu) * rstd * lw[col] + lb[col]);
      amax = fmaxf(amax, fabsf(h[k]));
    }
    amax = fmaxf(amax, __shfl_xor(amax, 1));
    amax = fmaxf(amax, __shfl_xor(amax, 2));
    unsigned short q[8];
    quant8(h, amax, q);
    ((uint4*)(a1 + (size_t)row * H))[t] = pack8(q);
  }
}

// ---------- GEMM: C[m,n] = sum_k A[m,k]*B[n,k], A/B bf16, fp32 acc ----------
// 128x256 tile, BK=64, 512 threads = 8 waves (2M x 4N), each wave 64x64
// (4x4 of 16x16x32 MFMA -> epilogues identical to the proven 128^2 version).
//
// Pipelined schedule (T3+T4+T5 from the technique catalog):
//   - 3 LDS stages (144 KiB): tile t in buf t%3; staging targets (t+2)%3,
//     so the overwriting global_load_lds for a slot is issued >=1 full
//     barrier-separated phase after that slot's last ds_read (no race).
//   - per K-tile: 2 phases (k-half 0 / k-half 1). Each phase:
//     8x ds_read_b128 | issue 3 global_load_lds (half-tile of t+2) |
//     s_barrier | lgkmcnt(0)+sched_barrier (rule #18) | setprio(1) |
//     16 MFMA | setprio(0) | s_barrier.
//   - counted vmcnt(6) once per tile (never 0 in steady state): drains
//     tile t+1's 6 loads, leaves tile t+2's 6 in flight across barriers.
//   - k-chunk XOR swizzle: read chunk quad^(row&3); staging keeps LDS dest
//     linear and inverse-swizzles the GLOBAL source chunk (rule #21).
// MODE 1: h = bf16(gelu_tanh(bf16(y+bias))) then fused MX-quant along N via
//   DPP row max -> quantized bf16 [M,N]
// MODE 2: out = bf16(bf16(resid) + bf16(y + bias)) -> float [M,N]
template <int MODE>
__global__ __launch_bounds__(512, 2) void gemm_mx(const unsigned short* __restrict__ A,
                                                  const unsigned short* __restrict__ B,
                                                  int M, int N, int K,
                                                  const float* __restrict__ bias,
                                                  const float* __restrict__ resid,
                                                  void* __restrict__ outp) {
  // [buf][khalf][rows*32] ; A: 128 rows, B: 256 rows, 32 ushorts (=one K-half) each
  __shared__ __align__(16) unsigned short As[3][2][128 * 32];   // 48 KiB
  __shared__ __align__(16) unsigned short Bs[3][2][256 * 32];   // 96 KiB

  const int tid = threadIdx.x;
  const int lane = tid & 63;
  const int wave = tid >> 6;        // 0..7
  const int lr = lane & 15;
  const int quad = lane >> 4;       // 0..3
  const int wr = (wave >> 2) * 64;  // 0 | 64
  const int wc = (wave & 3) * 64;   // 0 | 64 | 128 | 192

  const int m0 = blockIdx.y * 128;
  const int n0 = blockIdx.x * 256;

  // frag-read addressing (ushort units within one k-half block).
  // row r holds k-chunk c at position c^(r&3); row&3 == lr&3 here.
  const int xsw = (quad ^ (lr & 3)) << 3;
  const int lro = (wr + lr) * 32 + xsw;
  const int lco = (wc + lr) * 32 + xsw;

  // staging: LDS dest linear (unit u = loadIdx*512 + tid -> row u>>2, pos u&3);
  // global source chunk = pos ^ (row&3) so the read-side swizzle sees chunk quad.
  const int sr = tid >> 2;                       // 0..127
  const int sc = ((tid & 3) ^ (sr & 3)) << 3;    // ushort offset of source chunk
  const size_t aoff  = (size_t)(m0 + sr) * K + sc;
  const size_t boff0 = (size_t)(n0 + sr) * K + sc;
  const size_t boff1 = (size_t)(n0 + 128 + sr) * K + sc;
  const int lbase = (tid & ~63) * 8;             // wave-uniform LDS base (ushorts)

  const int NT = K >> 6;

  f32x4 acc[4][4];
#pragma unroll
  for (int i = 0; i < 4; ++i)
#pragma unroll
    for (int j = 0; j < 4; ++j) acc[i][j] = (f32x4){0.f, 0.f, 0.f, 0.f};

  // prologue: stage tiles 0 and 1 (12 loads), keep tile1's 6 in flight
#pragma unroll
  for (int pt = 0; pt < 2; ++pt)
#pragma unroll
    for (int s = 0; s < 2; ++s) {
      const size_t kadd = (size_t)pt * 64 + s * 32;
      gl2lds16(A + aoff + kadd, &As[pt][s][lbase]);
      gl2lds16(B + boff0 + kadd, &Bs[pt][s][lbase]);
      gl2lds16(B + boff1 + kadd, &Bs[pt][s][4096 + lbase]);
    }
  asm volatile("s_waitcnt vmcnt(6)" ::: "memory");
  __builtin_amdgcn_s_barrier();

  int buf = 0;
  for (int t = 0; t < NT; ++t) {
    int nbuf = buf + 2; if (nbuf >= 3) nbuf -= 3;
    const bool pf = (t + 2) < NT;
#pragma unroll
    for (int s = 0; s < 2; ++s) {
      bf16x8 af[4], bfr[4];
      const unsigned short* Ap = &As[buf][s][0];
      const unsigned short* Bp = &Bs[buf][s][0];
#pragma unroll
      for (int i = 0; i < 4; ++i) af[i] = *(const bf16x8*)(Ap + lro + i * 512);
#pragma unroll
      for (int j = 0; j < 4; ++j) bfr[j] = *(const bf16x8*)(Bp + lco + j * 512);
      if (pf) {
        const size_t kadd = (size_t)(t + 2) * 64 + s * 32;
        gl2lds16(A + aoff + kadd, &As[nbuf][s][lbase]);
        gl2lds16(B + boff0 + kadd, &Bs[nbuf][s][lbase]);
        gl2lds16(B + boff1 + kadd, &Bs[nbuf][s][4096 + lbase]);
      }
      __builtin_amdgcn_s_barrier();
      asm volatile("s_waitcnt lgkmcnt(0)" ::: "memory");
      __builtin_amdgcn_sched_barrier(0);      // rule #18: keep MFMA below the wait
      __builtin_amdgcn_s_setprio(1);
#pragma unroll
      for (int i = 0; i < 4; ++i)
#pragma unroll
        for (int j = 0; j < 4; ++j)
          acc[i][j] = __builtin_amdgcn_mfma_f32_16x16x32_bf16(af[i], bfr[j], acc[i][j], 0, 0, 0);
      __builtin_amdgcn_s_setprio(0);
      if (s == 1) {
        // tile-entry wait for t+1: drain tile t+1's loads, leave tile t+2's 6 in flight
        if (pf) asm volatile("s_waitcnt vmcnt(6)" ::: "memory");
        else    asm volatile("s_waitcnt vmcnt(0)" ::: "memory");
      }
      __builtin_amdgcn_s_barrier();
    }
    if (++buf == 3) buf = 0;
  }

  // epilogue: D mapping col = lane&15, row = quad*4 + reg   [m89-verified]
  if (MODE == 1) {
#pragma unroll
    for (int i = 0; i < 4; ++i) {
#pragma unroll
      for (int r = 0; r < 4; ++r) {
        const int gm = m0 + wr + i * 16 + quad * 4 + r;
        float g[4];
#pragma unroll
        for (int j = 0; j < 4; ++j) {
          float tt = bf16r(acc[i][j][r] + bias[n0 + wc + j * 16 + lr]);
          float u = 0.7978845608028654f * (tt + 0.044715f * tt * tt * tt);
          g[j] = bf16r(0.5f * tt * (1.0f + tanhf(u)));
        }
        // fused MX quant: 32-col block = {j0,j1} / {j2,j3} over this quad's lanes
        float a = quad_row_max(fmaxf(fabsf(g[0]), fabsf(g[1])));
        float b = quad_row_max(fmaxf(fabsf(g[2]), fabsf(g[3])));
        unsigned short q[4];
        if (a > 0.f) {
          float sc2, iv; mx_scales(a, sc2, iv);
          q[0] = quantv(g[0], sc2, iv); q[1] = quantv(g[1], sc2, iv);
        } else { q[0] = q[1] = 0; }
        if (b > 0.f) {
          float sc2, iv; mx_scales(b, sc2, iv);
          q[2] = quantv(g[2], sc2, iv); q[3] = quantv(g[3], sc2, iv);
        } else { q[2] = q[3] = 0; }
        unsigned short* orow = (unsigned short*)outp + (size_t)gm * N + n0 + wc + lr;
#pragma unroll
        for (int j = 0; j < 4; ++j) orow[j * 16] = q[j];
      }
    }
  } else {
#pragma unroll
    for (int i = 0; i < 4; ++i) {
#pragma unroll
      for (int j = 0; j < 4; ++j) {
#pragma unroll
        for (int r = 0; r < 4; ++r) {
          int gm = m0 + wr + i * 16 + quad * 4 + r;
          int gn = n0 + wc + j * 16 + lr;
          float h = bf16r(acc[i][j][r] + bias[gn]);
          float rr = bf16r(resid[(size_t)gm * N + gn]);
          ((float*)outp)[(size_t)gm * N + gn] = bf16r(rr + h);
        }
      }
    }
  }
  (void)M;
}

extern "C" void kernel_launch(void* const* d_in, const int* in_sizes, int n_in,
                              void* d_out, int out_size, void* d_ws, size_t ws_size,
                              hipStream_t stream) {
  const float* inputs = (const float*)d_in[0];  // [2,2048,2048]
  const float* ln_w   = (const float*)d_in[1];  // [2048]
  const float* ln_b   = (const float*)d_in[2];  // [2048]
  const float* W1     = (const float*)d_in[3];  // [8192,2048]
  const float* b1     = (const float*)d_in[4];  // [8192]
  const float* W2     = (const float*)d_in[5];  // [2048,8192]
  const float* b2     = (const float*)d_in[6];  // [2048]
  float* out = (float*)d_out;                   // [2,2048,2048] fp32 (bf16-valued)
  char* ws = (char*)d_ws;
  (void)in_sizes; (void)n_in; (void)out_size; (void)ws_size;

  // workspace layout (144 MiB total)
  unsigned short* qW1  = (unsigned short*)(ws);                      // 32 MiB
  unsigned short* qW2  = (unsigned short*)(ws + (size_t)33554432);   // 32 MiB
  unsigned short* a1   = (unsigned short*)(ws + (size_t)67108864);   // 16 MiB [4096,2048]
  unsigned short* act2 = (unsigned short*)(ws + (size_t)83886080);   // 64 MiB [4096,8192]

  const int M = 4096;

  // 1. merged prep: quantize W1+W2 and LN+quant the activations (one dispatch)
  prep_k<<<20480, 256, 0, stream>>>(W1, W2, inputs, ln_w, ln_b, qW1, qW2, a1);

  // 2. GEMM1 + bias + gelu + fused MX quant (DPP) -> quantized bf16 [4096,8192]
  gemm_mx<1><<<dim3(8192 / 256, M / 128), 512, 0, stream>>>(
      a1, qW1, M, 8192, 2048, b1, nullptr, (void*)act2);

  // 3. GEMM2 [4096,8192] x [2048,8192]^T + bias + residual -> fp32 out
  gemm_mx<2><<<dim3(2048 / 256, M / 128), 512, 0, stream>>>(
      act2, qW2, M, 2048, 8192, b2, inputs, (void*)out);
}

// Round 2
// 513.384 us; speedup vs baseline: 1.0877x; 1.0877x over previous
//
#include <hip/hip_runtime.h>

#define DEVI __device__ __forceinline__

typedef __bf16 bf16x8 __attribute__((ext_vector_type(8)));
typedef float f32x4 __attribute__((ext_vector_type(4)));

// ---------- exact bf16 RNE helpers ----------
DEVI unsigned short f2bf(float f) {
  unsigned u = __float_as_uint(f);
  u = (u + 0x7FFFu + ((u >> 16) & 1u)) >> 16;
  return (unsigned short)u;
}
DEVI float bf2f(unsigned short h) { return __uint_as_float(((unsigned)h) << 16); }
DEVI float bf16r(float f) { return bf2f(f2bf(f)); }

// ---------- fast MXINT8 scale from block amax (amax normal, >0) ----------
DEVI void mx_scales(float amax, float& scale, float& inv) {
  unsigned eb = __float_as_uint(amax) & 0x7f800000u;
  scale = __uint_as_float(eb - (6u << 23));          // 2^(e-6)
  inv   = __uint_as_float((260u << 23) - eb);        // 2^(6-e)
}

DEVI unsigned short quantv(float v, float scale, float inv) {
  float qv = rintf(v * inv);                          // RNE, matches jnp.round
  qv = fminf(fmaxf(qv, -128.f), 127.f);
  return f2bf(qv * scale);                            // exact in bf16
}

DEVI void quant8(const float* h, float amax, unsigned short* q) {
  if (amax > 0.f) {
    float scale, inv;
    mx_scales(amax, scale, inv);
#pragma unroll
    for (int k = 0; k < 8; ++k) q[k] = quantv(h[k], scale, inv);
  } else {
#pragma unroll
    for (int k = 0; k < 8; ++k) q[k] = 0;
  }
}

// ---------- 16-lane (DPP row) max reduction on the VALU pipe ----------
template <int N>
DEVI float qmax_step(float x) {
  int y = __builtin_amdgcn_update_dpp(0, __float_as_int(x), 0x120 | N, 0xF, 0xF, true);
  return fmaxf(x, __int_as_float(y));
}
DEVI float quad_row_max(float x) {
  x = qmax_step<1>(x);
  x = qmax_step<2>(x);
  x = qmax_step<4>(x);
  x = qmax_step<8>(x);
  return x;
}

// ---------- async global->LDS 16B ----------
DEVI void gl2lds16(const void* g, void* l) {
  __builtin_amdgcn_global_load_lds(
      (__attribute__((address_space(1))) void*)const_cast<void*>(g),
      (__attribute__((address_space(3))) void*)l, 16, 0, 0);
}

DEVI uint4 pack8(const unsigned short* q) {
  uint4 o;
  o.x = (unsigned)q[0] | ((unsigned)q[1] << 16);
  o.y = (unsigned)q[2] | ((unsigned)q[3] << 16);
  o.z = (unsigned)q[4] | ((unsigned)q[5] << 16);
  o.w = (unsigned)q[6] | ((unsigned)q[7] << 16);
  return o;
}

// ---------- merged prep: W1 quant | W2 quant | LN+quant in ONE dispatch ----------
__global__ __launch_bounds__(256) void prep_k(const float* __restrict__ W1,
                                              const float* __restrict__ W2,
                                              const float* __restrict__ X,
                                              const float* __restrict__ lw,
                                              const float* __restrict__ lb,
                                              unsigned short* __restrict__ qW1,
                                              unsigned short* __restrict__ qW2,
                                              unsigned short* __restrict__ a1) {
  __shared__ float red[4];
  const int bid = blockIdx.x;
  const int t = threadIdx.x;
  if (bid < 16384) {
    const float* src = (bid < 8192) ? W1 : W2;
    unsigned short* dst = (bid < 8192) ? qW1 : qW2;
    size_t idx = (size_t)(bid & 8191) * 256 + t;   // 8 elems/thread
    float4 v0 = ((const float4*)src)[idx * 2];
    float4 v1 = ((const float4*)src)[idx * 2 + 1];
    float h[8] = {v0.x, v0.y, v0.z, v0.w, v1.x, v1.y, v1.z, v1.w};
    float amax = 0.f;
#pragma unroll
    for (int k = 0; k < 8; ++k) amax = fmaxf(amax, fabsf(h[k]));
    amax = fmaxf(amax, __shfl_xor(amax, 1));   // 4 consecutive lanes = one 32-block
    amax = fmaxf(amax, __shfl_xor(amax, 2));
    unsigned short q[8];
    quant8(h, amax, q);
    ((uint4*)dst)[idx] = pack8(q);
  } else {
    const int H = 2048;
    const int row = bid - 16384;
    const int lane = t & 63, wave = t >> 6;
    const float* xr = X + (size_t)row * H;
    float4 v0 = ((const float4*)xr)[2 * t];
    float4 v1 = ((const float4*)xr)[2 * t + 1];
    float x[8] = {bf16r(v0.x), bf16r(v0.y), bf16r(v0.z), bf16r(v0.w),
                  bf16r(v1.x), bf16r(v1.y), bf16r(v1.z), bf16r(v1.w)};
    float s = 0.f;
#pragma unroll
    for (int k = 0; k < 8; ++k) s += x[k];
#pragma unroll
    for (int o = 32; o; o >>= 1) s += __shfl_xor(s, o);
    if (lane == 0) red[wave] = s;
    __syncthreads();
    float mu = (red[0] + red[1] + red[2] + red[3]) * (1.0f / H);
    __syncthreads();
    float v = 0.f;
#pragma unroll
    for (int k = 0; k < 8; ++k) { float d = x[k] - mu; v += d * d; }
#pragma unroll
    for (int o = 32; o; o >>= 1) v += __shfl_xor(v, o);
    if (lane == 0) red[wave] = v;
    __syncthreads();
    float var = (red[0] + red[1] + red[2] + red[3]) * (1.0f / H);
    float rstd = 1.0f / sqrtf(var + 1e-5f);
    float h[8];
    float amax = 0.f;
#pragma unroll
    for (int k = 0; k < 8; ++k) {
      int col = t * 8 + k;
      h[k] = bf16r((x[k] - mu) * rstd * lw[col] + lb[col]);
      amax = fmaxf(amax, fabsf(h[k]));
    }
    amax = fmaxf(amax, __shfl_xor(amax, 1));
    amax = fmaxf(amax, __shfl_xor(amax, 2));
    unsigned short q[8];
    quant8(h, amax, q);
    ((uint4*)(a1 + (size_t)row * H))[t] = pack8(q);
  }
}

// ---------- GEMM: C[m,n] = sum_k A[m,k]*B[n,k], A/B bf16, fp32 acc ----------
// 128x256 tile, BK=64, 512 threads = 8 waves (2M x 4N), each wave 64x64.
//
// LDS geometry = round-0's measured-conflict-free layout: row-major
// [rows][64 ushorts], 8 chunks of 8 ushorts per row, chunk c stored at
// position c^(row&7). Read chunk (s*4+quad)^(lr&7) -> banks 4c..4c+3,
// 2 lanes/bank (free). Staging keeps LDS dest linear and inverse-swizzles
// the GLOBAL source chunk (rule #21).
//
// Pipelined schedule (T3+T4+T5):
//   - 3 LDS stages (144 KiB): tile t in buf t%3; staging targets (t+2)%3.
//   - per K-tile: 2 phases (chunk-half 0 / 1). Each phase:
//     8x ds_read_b128 | issue 3 global_load_lds rounds (of tile t+2) |
//     s_barrier | lgkmcnt(0)+sched_barrier (rule #18) | setprio(1) |
//     16 MFMA | setprio(0) | s_barrier.
//   - counted vmcnt(6) once per tile (never 0 in steady state): drains
//     tile t+1's 6 loads, leaves tile t+2's 6 in flight across barriers.
// MODE 1: h = bf16(gelu_tanh(bf16(y+bias))) then fused MX-quant along N via
//   DPP row max -> quantized bf16 [M,N]
// MODE 2: out = bf16(bf16(resid) + bf16(y + bias)) -> float [M,N]
template <int MODE>
__global__ __launch_bounds__(512, 2) void gemm_mx(const unsigned short* __restrict__ A,
                                                  const unsigned short* __restrict__ B,
                                                  int M, int N, int K,
                                                  const float* __restrict__ bias,
                                                  const float* __restrict__ resid,
                                                  void* __restrict__ outp) {
  __shared__ __align__(16) unsigned short As[3][128 * 64];   // 3 x 16 KiB
  __shared__ __align__(16) unsigned short Bs[3][256 * 64];   // 3 x 32 KiB

  const int tid = threadIdx.x;
  const int lane = tid & 63;
  const int wave = tid >> 6;        // 0..7
  const int lr = lane & 15;
  const int quad = lane >> 4;       // 0..3
  const int wr = (wave >> 2) * 64;  // 0 | 64
  const int wc = (wave & 3) * 64;   // 0 | 64 | 128 | 192

  const int m0 = blockIdx.y * 128;
  const int n0 = blockIdx.x * 256;

  // frag-read addressing (ushort units): row*64 + ch*8, ch = (s*4+quad)^(lr&7)
  const int chA = quad ^ (lr & 7);                 // phase 0 chunk; phase 1 = chA^4
  const int lroA = (wr + lr) * 64;
  const int lcoA = (wc + lr) * 64;

  // staging: unit u = j*512 + tid -> row j*64 + (tid>>3), pos tid&7;
  // global source chunk = pos ^ (row&7) = (tid&7) ^ ((tid>>3)&7)  (j*64 == 0 mod 8)
  const int sr8 = tid >> 3;                        // 0..63
  const int sch = (tid & 7) ^ (sr8 & 7);
  size_t aoff[2], boff[4];
#pragma unroll
  for (int j = 0; j < 2; ++j) aoff[j] = (size_t)(m0 + j * 64 + sr8) * K + sch * 8;
#pragma unroll
  for (int j = 0; j < 4; ++j) boff[j] = (size_t)(n0 + j * 64 + sr8) * K + sch * 8;
  const int lb = (tid & ~63) * 8;                  // wave-uniform LDS base (ushorts)

  const int NT = K >> 6;

  f32x4 acc[4][4];
#pragma unroll
  for (int i = 0; i < 4; ++i)
#pragma unroll
    for (int j = 0; j < 4; ++j) acc[i][j] = (f32x4){0.f, 0.f, 0.f, 0.f};

  // prologue: stage tiles 0 and 1 (6 loads each, tile-0 loads oldest)
#pragma unroll
  for (int pt = 0; pt < 2; ++pt) {
    const size_t kadd = (size_t)pt * 64;
#pragma unroll
    for (int j = 0; j < 2; ++j) gl2lds16(A + aoff[j] + kadd, &As[pt][j * 4096 + lb]);
#pragma unroll
    for (int j = 0; j < 4; ++j) gl2lds16(B + boff[j] + kadd, &Bs[pt][j * 4096 + lb]);
  }
  asm volatile("s_waitcnt vmcnt(6)" ::: "memory");  // tile 0 resident
  __builtin_amdgcn_s_barrier();

  int buf = 0;
  for (int t = 0; t < NT; ++t) {
    int nbuf = buf + 2; if (nbuf >= 3) nbuf -= 3;
    const bool pf = (t + 2) < NT;
    const size_t kadd = (size_t)(t + 2) * 64;

    // ---- phase 0: chunks chA ----
    {
      bf16x8 af[4], bfr[4];
      const unsigned short* Ap = &As[buf][lroA + chA * 8];
      const unsigned short* Bp = &Bs[buf][lcoA + chA * 8];
#pragma unroll
      for (int i = 0; i < 4; ++i) af[i] = *(const bf16x8*)(Ap + i * 1024);
#pragma unroll
      for (int j = 0; j < 4; ++j) bfr[j] = *(const bf16x8*)(Bp + j * 1024);
      if (pf) {
        gl2lds16(A + aoff[0] + kadd, &As[nbuf][lb]);
        gl2lds16(B + boff[0] + kadd, &Bs[nbuf][lb]);
        gl2lds16(B + boff[1] + kadd, &Bs[nbuf][4096 + lb]);
      }
      __builtin_amdgcn_s_barrier();
      asm volatile("s_waitcnt lgkmcnt(0)" ::: "memory");
      __builtin_amdgcn_sched_barrier(0);      // rule #18
      __builtin_amdgcn_s_setprio(1);
#pragma unroll
      for (int i = 0; i < 4; ++i)
#pragma unroll
        for (int j = 0; j < 4; ++j)
          acc[i][j] = __builtin_amdgcn_mfma_f32_16x16x32_bf16(af[i], bfr[j], acc[i][j], 0, 0, 0);
      __builtin_amdgcn_s_setprio(0);
      __builtin_amdgcn_s_barrier();
    }

    // ---- phase 1: chunks chA^4 ----
    {
      bf16x8 af[4], bfr[4];
      const unsigned short* Ap = &As[buf][lroA + (chA ^ 4) * 8];
      const unsigned short* Bp = &Bs[buf][lcoA + (chA ^ 4) * 8];
#pragma unroll
      for (int i = 0; i < 4; ++i) af[i] = *(const bf16x8*)(Ap + i * 1024);
#pragma unroll
      for (int j = 0; j < 4; ++j) bfr[j] = *(const bf16x8*)(Bp + j * 1024);
      if (pf) {
        gl2lds16(A + aoff[1] + kadd, &As[nbuf][4096 + lb]);
        gl2lds16(B + boff[2] + kadd, &Bs[nbuf][8192 + lb]);
        gl2lds16(B + boff[3] + kadd, &Bs[nbuf][12288 + lb]);
      }
      __builtin_amdgcn_s_barrier();
      asm volatile("s_waitcnt lgkmcnt(0)" ::: "memory");
      __builtin_amdgcn_sched_barrier(0);
      __builtin_amdgcn_s_setprio(1);
#pragma unroll
      for (int i = 0; i < 4; ++i)
#pragma unroll
        for (int j = 0; j < 4; ++j)
          acc[i][j] = __builtin_amdgcn_mfma_f32_16x16x32_bf16(af[i], bfr[j], acc[i][j], 0, 0, 0);
      __builtin_amdgcn_s_setprio(0);
      // tile-end wait: drain tile t+1's 6 loads, leave tile t+2's 6 in flight
      if (pf) asm volatile("s_waitcnt vmcnt(6)" ::: "memory");
      else    asm volatile("s_waitcnt vmcnt(0)" ::: "memory");
      __builtin_amdgcn_s_barrier();
    }
    if (++buf == 3) buf = 0;
  }

  // epilogue: D mapping col = lane&15, row = quad*4 + reg   [m89-verified]
  if (MODE == 1) {
#pragma unroll
    for (int i = 0; i < 4; ++i) {
#pragma unroll
      for (int r = 0; r < 4; ++r) {
        const int gm = m0 + wr + i * 16 + quad * 4 + r;
        float g[4];
#pragma unroll
        for (int j = 0; j < 4; ++j) {
          float tt = bf16r(acc[i][j][r] + bias[n0 + wc + j * 16 + lr]);
          float u = 0.7978845608028654f * (tt + 0.044715f * tt * tt * tt);
          g[j] = bf16r(0.5f * tt * (1.0f + tanhf(u)));
        }
        // fused MX quant: 32-col block = {j0,j1} / {j2,j3} over this quad's lanes
        float a = quad_row_max(fmaxf(fabsf(g[0]), fabsf(g[1])));
        float b = quad_row_max(fmaxf(fabsf(g[2]), fabsf(g[3])));
        unsigned short q[4];
        if (a > 0.f) {
          float sc2, iv; mx_scales(a, sc2, iv);
          q[0] = quantv(g[0], sc2, iv); q[1] = quantv(g[1], sc2, iv);
        } else { q[0] = q[1] = 0; }
        if (b > 0.f) {
          float sc2, iv; mx_scales(b, sc2, iv);
          q[2] = quantv(g[2], sc2, iv); q[3] = quantv(g[3], sc2, iv);
        } else { q[2] = q[3] = 0; }
        unsigned short* orow = (unsigned short*)outp + (size_t)gm * N + n0 + wc + lr;
#pragma unroll
        for (int j = 0; j < 4; ++j) orow[j * 16] = q[j];
      }
    }
  } else {
#pragma unroll
    for (int i = 0; i < 4; ++i) {
#pragma unroll
      for (int j = 0; j < 4; ++j) {
#pragma unroll
        for (int r = 0; r < 4; ++r) {
          int gm = m0 + wr + i * 16 + quad * 4 + r;
          int gn = n0 + wc + j * 16 + lr;
          float h = bf16r(acc[i][j][r] + bias[gn]);
          float rr = bf16r(resid[(size_t)gm * N + gn]);
          ((float*)outp)[(size_t)gm * N + gn] = bf16r(rr + h);
        }
      }
    }
  }
  (void)M;
}

extern "C" void kernel_launch(void* const* d_in, const int* in_sizes, int n_in,
                              void* d_out, int out_size, void* d_ws, size_t ws_size,
                              hipStream_t stream) {
  const float* inputs = (const float*)d_in[0];  // [2,2048,2048]
  const float* ln_w   = (const float*)d_in[1];  // [2048]
  const float* ln_b   = (const float*)d_in[2];  // [2048]
  const float* W1     = (const float*)d_in[3];  // [8192,2048]
  const float* b1     = (const float*)d_in[4];  // [8192]
  const float* W2     = (const float*)d_in[5];  // [2048,8192]
  const float* b2     = (const float*)d_in[6];  // [2048]
  float* out = (float*)d_out;                   // [2,2048,2048] fp32 (bf16-valued)
  char* ws = (char*)d_ws;
  (void)in_sizes; (void)n_in; (void)out_size; (void)ws_size;

  // workspace layout (144 MiB total)
  unsigned short* qW1  = (unsigned short*)(ws);                      // 32 MiB
  unsigned short* qW2  = (unsigned short*)(ws + (size_t)33554432);   // 32 MiB
  unsigned short* a1   = (unsigned short*)(ws + (size_t)67108864);   // 16 MiB [4096,2048]
  unsigned short* act2 = (unsigned short*)(ws + (size_t)83886080);   // 64 MiB [4096,8192]

  const int M = 4096;

  // 1. merged prep: quantize W1+W2 and LN+quant the activations (one dispatch)
  prep_k<<<20480, 256, 0, stream>>>(W1, W2, inputs, ln_w, ln_b, qW1, qW2, a1);

  // 2. GEMM1 + bias + gelu + fused MX quant (DPP) -> quantized bf16 [4096,8192]
  gemm_mx<1><<<dim3(8192 / 256, M / 128), 512, 0, stream>>>(
      a1, qW1, M, 8192, 2048, b1, nullptr, (void*)act2);

  // 3. GEMM2 [4096,8192] x [2048,8192]^T + bias + residual -> fp32 out
  gemm_mx<2><<<dim3(2048 / 256, M / 128), 512, 0, stream>>>(
      act2, qW2, M, 2048, 8192, b2, inputs, (void*)out);
}